// Round 1
// baseline (1491.589 us; speedup 1.0000x reference)
//
#include <hip/hip_runtime.h>
#include <math.h>

#define NF 128   // feature dim (in == out == 128)

// K0: sup = alpha * h0   (folds the alpha*h0 term into the scatter target)
__global__ __launch_bounds__(256) void init_support_kernel(
    const float* __restrict__ h0, float* __restrict__ sup,
    const float* __restrict__ alpha_p, int total4)
{
    int i = blockIdx.x * 256 + threadIdx.x;
    if (i >= total4) return;
    float alpha = *alpha_p;
    float4 h = ((const float4*)h0)[i];
    float4 s;
    s.x = alpha * h.x; s.y = alpha * h.y; s.z = alpha * h.z; s.w = alpha * h.w;
    ((float4*)sup)[i] = s;
}

// K1: sup[row] += (1-alpha) * val * input[col]
// 32 threads per edge, float4 gather (512B coalesced per edge), 4 atomics/lane.
__global__ __launch_bounds__(256) void scatter_edges_kernel(
    const float* __restrict__ x, const int* __restrict__ erow,
    const int* __restrict__ ecol, const float* __restrict__ evalv,
    float* __restrict__ sup, const float* __restrict__ alpha_p, int E_)
{
    int t = blockIdx.x * 256 + threadIdx.x;
    int e = t >> 5;
    if (e >= E_) return;
    int lane = t & 31;
    float oma = 1.0f - *alpha_p;
    int row = erow[e];
    int col = ecol[e];
    float v = evalv[e] * oma;
    float4 m = *((const float4*)(x + (size_t)col * NF) + lane);
    float* dst = sup + (size_t)row * NF + lane * 4;
    atomicAdd(dst + 0, v * m.x);
    atomicAdd(dst + 1, v * m.y);
    atomicAdd(dst + 2, v * m.z);
    atomicAdd(dst + 3, v * m.w);
}

// K2: out = theta*(sup@W) + (1-theta)*sup + input
// W (128x128 fp32 = 64KB) staged in LDS. Block = 256 threads covers 32 rows.
// Each thread: 4 rows x 4 cols register tile; k unrolled by 4 so sup loads
// become float4.
__global__ __launch_bounds__(256) void gemm_epilogue_kernel(
    const float* __restrict__ sup, const float* __restrict__ W,
    const float* __restrict__ inp, float* __restrict__ out,
    const float* __restrict__ lamda_p, const int* __restrict__ l_p, int n_rows)
{
    __shared__ float Ws[NF * NF];  // 64 KB
    int tid = threadIdx.x;
    for (int i = tid; i < NF * NF / 4; i += 256)
        ((float4*)Ws)[i] = ((const float4*)W)[i];
    __syncthreads();

    float theta = logf((*lamda_p) / (float)(*l_p) + 1.0f);
    float omt = 1.0f - theta;

    int m0   = blockIdx.x * 32;
    int tcol = tid & 31;        // 32 col-groups * 4 = 128 cols
    int trow = tid >> 5;        // 8 row-groups * 4 = 32 rows
    int n    = tcol * 4;
    int mbase = m0 + trow * 4;

    // clamp row indices so last partial block loads stay in-bounds
    int mr[4];
#pragma unroll
    for (int r = 0; r < 4; r++) {
        int m = mbase + r;
        mr[r] = (m < n_rows) ? m : (n_rows - 1);
    }

    float acc[4][4] = {};
    for (int k = 0; k < NF; k += 4) {
        float4 srow[4];
#pragma unroll
        for (int r = 0; r < 4; r++)
            srow[r] = *(const float4*)&sup[(size_t)mr[r] * NF + k];
#pragma unroll
        for (int kk = 0; kk < 4; kk++) {
            float4 w = *(const float4*)&Ws[(k + kk) * NF + n];
#pragma unroll
            for (int r = 0; r < 4; r++) {
                float s = (&srow[r].x)[kk];
                acc[r][0] += s * w.x;
                acc[r][1] += s * w.y;
                acc[r][2] += s * w.z;
                acc[r][3] += s * w.w;
            }
        }
    }

#pragma unroll
    for (int r = 0; r < 4; r++) {
        int m = mbase + r;
        if (m >= n_rows) break;
        float4 sv = *(const float4*)&sup[(size_t)m * NF + n];
        float4 iv = *(const float4*)&inp[(size_t)m * NF + n];
        float4 o;
        o.x = theta * acc[r][0] + omt * sv.x + iv.x;
        o.y = theta * acc[r][1] + omt * sv.y + iv.y;
        o.z = theta * acc[r][2] + omt * sv.z + iv.z;
        o.w = theta * acc[r][3] + omt * sv.w + iv.w;
        *(float4*)&out[(size_t)m * NF + n] = o;
    }
}

extern "C" void kernel_launch(void* const* d_in, const int* in_sizes, int n_in,
                              void* d_out, int out_size, void* d_ws, size_t ws_size,
                              hipStream_t stream) {
    const float* x       = (const float*)d_in[0];
    const float* h0      = (const float*)d_in[1];
    const int*   erow    = (const int*)d_in[2];
    const int*   ecol    = (const int*)d_in[3];
    const float* evalv   = (const float*)d_in[4];
    const float* W       = (const float*)d_in[5];
    const float* lamda_p = (const float*)d_in[6];
    const float* alpha_p = (const float*)d_in[7];
    const int*   l_p     = (const int*)d_in[8];

    int N_ = in_sizes[0] / NF;   // 50000
    int E_ = in_sizes[2];        // 800000

    float* sup = (float*)d_ws;   // N*128 fp32 = 25.6 MB scratch
    float* out = (float*)d_out;

    int total4 = N_ * NF / 4;
    init_support_kernel<<<(total4 + 255) / 256, 256, 0, stream>>>(h0, sup, alpha_p, total4);

    long long ethreads = (long long)E_ * 32;
    scatter_edges_kernel<<<(int)((ethreads + 255) / 256), 256, 0, stream>>>(
        x, erow, ecol, evalv, sup, alpha_p, E_);

    gemm_epilogue_kernel<<<(N_ + 31) / 32, 256, 0, stream>>>(
        sup, W, x, out, lamda_p, l_p, N_);
}

// Round 4
// 391.512 us; speedup vs baseline: 3.8098x; 3.8098x over previous
//
#include <hip/hip_runtime.h>
#include <math.h>

#define NF 128   // feature dim (in == out == 128)

// ---- CSR build ------------------------------------------------------------

__global__ __launch_bounds__(256) void zero_kernel(int* __restrict__ p, int n) {
    int i = blockIdx.x * 256 + threadIdx.x;
    if (i < n) p[i] = 0;
}

__global__ __launch_bounds__(256) void hist_kernel(
    const int* __restrict__ erow, int* __restrict__ cnt, int E_) {
    int e = blockIdx.x * 256 + threadIdx.x;
    if (e < E_) atomicAdd(&cnt[erow[e]], 1);
}

// single-block exclusive scan over cnt[N] -> off[N+1], pos[N]=off[N-range]
__global__ __launch_bounds__(1024) void scan_kernel(
    const int* __restrict__ cnt, int* __restrict__ off, int* __restrict__ pos, int N_) {
    __shared__ int buf[1024];
    __shared__ int carry;
    int t = threadIdx.x;
    if (t == 0) carry = 0;
    __syncthreads();
    for (int base = 0; base < N_; base += 1024) {
        int i = base + t;
        int v = (i < N_) ? cnt[i] : 0;
        buf[t] = v;
        __syncthreads();
        for (int d = 1; d < 1024; d <<= 1) {
            int add = (t >= d) ? buf[t - d] : 0;
            __syncthreads();
            buf[t] += add;
            __syncthreads();
        }
        int incl = buf[t];
        int total = buf[1023];
        int run = carry;
        if (i < N_) {
            int o = run + incl - v;   // exclusive
            off[i] = o;
            pos[i] = o;
        }
        __syncthreads();
        if (t == 0) carry = run + total;
        __syncthreads();
    }
    if (t == 0) off[N_] = carry;
}

__global__ __launch_bounds__(256) void fill_kernel(
    const int* __restrict__ erow, const int* __restrict__ ecol,
    const float* __restrict__ evalv, int* __restrict__ pos,
    int* __restrict__ scol, float* __restrict__ sval, int E_) {
    int e = blockIdx.x * 256 + threadIdx.x;
    if (e >= E_) return;
    int p = atomicAdd(&pos[erow[e]], 1);
    scol[p] = ecol[e];
    sval[p] = evalv[e];
}

// ---- SpMM: one wave per row, register accumulation, single write ----------

__global__ __launch_bounds__(256) void spmm_kernel(
    const float* __restrict__ x, const float* __restrict__ h0,
    const int* __restrict__ off, const int* __restrict__ scol,
    const float* __restrict__ sval, float* __restrict__ sup,
    const float* __restrict__ alpha_p, int N_) {
    int w = (blockIdx.x * 256 + threadIdx.x) >> 6;   // wave id == row
    if (w >= N_) return;
    int lane = threadIdx.x & 63;
    float alpha = *alpha_p;
    int s = off[w], e = off[w + 1];
    float2 acc = {0.f, 0.f};
    int i = s;
    // 2-edge unroll for ILP (independent gathers in flight)
    for (; i + 1 < e; i += 2) {
        int c0 = scol[i], c1 = scol[i + 1];
        float v0 = sval[i], v1 = sval[i + 1];
        float2 a = *((const float2*)(x + (size_t)c0 * NF) + lane);
        float2 b = *((const float2*)(x + (size_t)c1 * NF) + lane);
        acc.x += v0 * a.x + v1 * b.x;
        acc.y += v0 * a.y + v1 * b.y;
    }
    if (i < e) {
        int c0 = scol[i];
        float v0 = sval[i];
        float2 a = *((const float2*)(x + (size_t)c0 * NF) + lane);
        acc.x += v0 * a.x;
        acc.y += v0 * a.y;
    }
    float2 h = *((const float2*)(h0 + (size_t)w * NF) + lane);
    float oma = 1.0f - alpha;
    float2 o;
    o.x = oma * acc.x + alpha * h.x;
    o.y = oma * acc.y + alpha * h.y;
    *((float2*)(sup + (size_t)w * NF) + lane) = o;
}

// ---- GEMM + epilogue: out = theta*(sup@W) + (1-theta)*sup + input ---------

__global__ __launch_bounds__(256) void gemm_epilogue_kernel(
    const float* __restrict__ sup, const float* __restrict__ W,
    const float* __restrict__ inp, float* __restrict__ out,
    const float* __restrict__ lamda_p, const int* __restrict__ l_p, int n_rows) {
    __shared__ float Ws[NF * NF];  // 64 KB
    int tid = threadIdx.x;
    for (int i = tid; i < NF * NF / 4; i += 256)
        ((float4*)Ws)[i] = ((const float4*)W)[i];
    __syncthreads();

    float theta = logf((*lamda_p) / (float)(*l_p) + 1.0f);
    float omt = 1.0f - theta;

    int m0   = blockIdx.x * 32;
    int tcol = tid & 31;
    int trow = tid >> 5;
    int n    = tcol * 4;
    int mbase = m0 + trow * 4;

    int mr[4];
#pragma unroll
    for (int r = 0; r < 4; r++) {
        int m = mbase + r;
        mr[r] = (m < n_rows) ? m : (n_rows - 1);
    }

    float acc[4][4] = {};
    for (int k = 0; k < NF; k += 4) {
        float4 srow[4];
#pragma unroll
        for (int r = 0; r < 4; r++)
            srow[r] = *(const float4*)&sup[(size_t)mr[r] * NF + k];
#pragma unroll
        for (int kk = 0; kk < 4; kk++) {
            float4 w = *(const float4*)&Ws[(k + kk) * NF + n];
#pragma unroll
            for (int r = 0; r < 4; r++) {
                float s = (&srow[r].x)[kk];
                acc[r][0] += s * w.x;
                acc[r][1] += s * w.y;
                acc[r][2] += s * w.z;
                acc[r][3] += s * w.w;
            }
        }
    }

#pragma unroll
    for (int r = 0; r < 4; r++) {
        int m = mbase + r;
        if (m >= n_rows) break;
        float4 sv = *(const float4*)&sup[(size_t)m * NF + n];
        float4 iv = *(const float4*)&inp[(size_t)m * NF + n];
        float4 o;
        o.x = theta * acc[r][0] + omt * sv.x + iv.x;
        o.y = theta * acc[r][1] + omt * sv.y + iv.y;
        o.z = theta * acc[r][2] + omt * sv.z + iv.z;
        o.w = theta * acc[r][3] + omt * sv.w + iv.w;
        *(float4*)&out[(size_t)m * NF + n] = o;
    }
}

extern "C" void kernel_launch(void* const* d_in, const int* in_sizes, int n_in,
                              void* d_out, int out_size, void* d_ws, size_t ws_size,
                              hipStream_t stream) {
    const float* x       = (const float*)d_in[0];
    const float* h0      = (const float*)d_in[1];
    const int*   erow    = (const int*)d_in[2];
    const int*   ecol    = (const int*)d_in[3];
    const float* evalv   = (const float*)d_in[4];
    const float* W       = (const float*)d_in[5];
    const float* lamda_p = (const float*)d_in[6];
    const float* alpha_p = (const float*)d_in[7];
    const int*   l_p     = (const int*)d_in[8];

    int N_ = in_sizes[0] / NF;   // 50000
    int E_ = in_sizes[2];        // 800000

    // workspace layout (256B-aligned slabs)
    char* ws = (char*)d_ws;
    size_t o = 0;
    auto alloc = [&](size_t bytes) { char* p = ws + o; o = (o + bytes + 255) & ~(size_t)255; return p; };
    float* sup  = (float*)alloc((size_t)N_ * NF * sizeof(float)); // 25.6 MB
    int*   cnt  = (int*)  alloc((size_t)N_ * sizeof(int));
    int*   off  = (int*)  alloc((size_t)(N_ + 1) * sizeof(int));
    int*   pos  = (int*)  alloc((size_t)N_ * sizeof(int));
    int*   scol = (int*)  alloc((size_t)E_ * sizeof(int));
    float* sval = (float*)alloc((size_t)E_ * sizeof(float));

    float* out = (float*)d_out;

    zero_kernel<<<(N_ + 255) / 256, 256, 0, stream>>>(cnt, N_);
    hist_kernel<<<(E_ + 255) / 256, 256, 0, stream>>>(erow, cnt, E_);
    scan_kernel<<<1, 1024, 0, stream>>>(cnt, off, pos, N_);
    fill_kernel<<<(E_ + 255) / 256, 256, 0, stream>>>(erow, ecol, evalv, pos, scol, sval, E_);

    int waves = N_;                       // one wave per row
    int blocks = (waves * 64 + 255) / 256;
    spmm_kernel<<<blocks, 256, 0, stream>>>(x, h0, off, scol, sval, sup, alpha_p, N_);

    gemm_epilogue_kernel<<<(N_ + 31) / 32, 256, 0, stream>>>(
        sup, W, x, out, lamda_p, l_p, N_);
}

// Round 6
// 311.070 us; speedup vs baseline: 4.7950x; 1.2586x over previous
//
#include <hip/hip_runtime.h>
#include <math.h>

#define NF 128      // feature dim (in == out == 128)
#define SCAN_B 1024 // scan chunk size

// ---- CSR build ------------------------------------------------------------

__global__ __launch_bounds__(256) void zero_kernel(int* __restrict__ p, int n) {
    int i = blockIdx.x * 256 + threadIdx.x;
    if (i < n) p[i] = 0;
}

__global__ __launch_bounds__(256) void hist_kernel(
    const int* __restrict__ erow, int* __restrict__ cnt, int E_) {
    int e = blockIdx.x * 256 + threadIdx.x;
    if (e < E_) atomicAdd(&cnt[erow[e]], 1);
}

// Phase A: per-block sums of cnt chunks
__global__ __launch_bounds__(SCAN_B) void scanA_kernel(
    const int* __restrict__ cnt, int* __restrict__ bsum, int N_) {
    __shared__ int buf[SCAN_B];
    int t = threadIdx.x;
    int i = blockIdx.x * SCAN_B + t;
    buf[t] = (i < N_) ? cnt[i] : 0;
    __syncthreads();
    for (int d = SCAN_B / 2; d > 0; d >>= 1) {
        if (t < d) buf[t] += buf[t + d];
        __syncthreads();
    }
    if (t == 0) bsum[blockIdx.x] = buf[0];
}

// Phase B: exclusive scan of block sums (nb <= 64) in one wave; total -> off[N]
__global__ __launch_bounds__(64) void scanB_kernel(
    const int* __restrict__ bsum, int* __restrict__ bpre,
    int* __restrict__ off_total, int nb) {
    int t = threadIdx.x;
    int v0 = (t < nb) ? bsum[t] : 0;
    int v = v0;
    for (int d = 1; d < 64; d <<= 1) {
        int u = __shfl_up(v, d, 64);
        if (t >= d) v += u;
    }
    if (t < nb) bpre[t] = v - v0;      // exclusive prefix
    if (t == nb - 1) *off_total = v;   // grand total -> off[N]
}

// Phase C: per-chunk exclusive scan + block prefix -> off[], pos[]
__global__ __launch_bounds__(SCAN_B) void scanC_kernel(
    const int* __restrict__ cnt, const int* __restrict__ bpre,
    int* __restrict__ off, int* __restrict__ pos, int N_) {
    __shared__ int buf[SCAN_B];
    int t = threadIdx.x;
    int i = blockIdx.x * SCAN_B + t;
    int v = (i < N_) ? cnt[i] : 0;
    buf[t] = v;
    __syncthreads();
    for (int d = 1; d < SCAN_B; d <<= 1) {
        int add = (t >= d) ? buf[t - d] : 0;
        __syncthreads();
        buf[t] += add;
        __syncthreads();
    }
    if (i < N_) {
        int o = bpre[blockIdx.x] + buf[t] - v;  // exclusive
        off[i] = o;
        pos[i] = o;
    }
}

__global__ __launch_bounds__(256) void fill_kernel(
    const int* __restrict__ erow, const int* __restrict__ ecol,
    const float* __restrict__ evalv, int* __restrict__ pos,
    int* __restrict__ scol, float* __restrict__ sval, int E_) {
    int e = blockIdx.x * 256 + threadIdx.x;
    if (e >= E_) return;
    int p = atomicAdd(&pos[erow[e]], 1);
    scol[p] = ecol[e];
    sval[p] = evalv[e];
}

// ---- SpMM: one wave per row, register accumulation, single write ----------

__global__ __launch_bounds__(256) void spmm_kernel(
    const float* __restrict__ x, const float* __restrict__ h0,
    const int* __restrict__ off, const int* __restrict__ scol,
    const float* __restrict__ sval, float* __restrict__ sup,
    const float* __restrict__ alpha_p, int N_) {
    int w = (blockIdx.x * 256 + threadIdx.x) >> 6;   // wave id == row
    if (w >= N_) return;
    int lane = threadIdx.x & 63;
    float alpha = *alpha_p;
    int s = off[w], e = off[w + 1];
    float2 acc = {0.f, 0.f};
    int i = s;
    // 4-edge unroll: 4 independent gathers in flight
    for (; i + 3 < e; i += 4) {
        int c0 = scol[i], c1 = scol[i + 1], c2 = scol[i + 2], c3 = scol[i + 3];
        float v0 = sval[i], v1 = sval[i + 1], v2 = sval[i + 2], v3 = sval[i + 3];
        float2 a = *((const float2*)(x + (size_t)c0 * NF) + lane);
        float2 b = *((const float2*)(x + (size_t)c1 * NF) + lane);
        float2 c = *((const float2*)(x + (size_t)c2 * NF) + lane);
        float2 d = *((const float2*)(x + (size_t)c3 * NF) + lane);
        acc.x += v0 * a.x + v1 * b.x + v2 * c.x + v3 * d.x;
        acc.y += v0 * a.y + v1 * b.y + v2 * c.y + v3 * d.y;
    }
    for (; i < e; i++) {
        int c0 = scol[i];
        float v0 = sval[i];
        float2 a = *((const float2*)(x + (size_t)c0 * NF) + lane);
        acc.x += v0 * a.x;
        acc.y += v0 * a.y;
    }
    float2 h = *((const float2*)(h0 + (size_t)w * NF) + lane);
    float oma = 1.0f - alpha;
    float2 o;
    o.x = oma * acc.x + alpha * h.x;
    o.y = oma * acc.y + alpha * h.y;
    *((float2*)(sup + (size_t)w * NF) + lane) = o;
}

// ---- GEMM + epilogue: out = theta*(sup@W) + (1-theta)*sup + input ---------

__global__ __launch_bounds__(256) void gemm_epilogue_kernel(
    const float* __restrict__ sup, const float* __restrict__ W,
    const float* __restrict__ inp, float* __restrict__ out,
    const float* __restrict__ lamda_p, const int* __restrict__ l_p, int n_rows) {
    __shared__ float Ws[NF * NF];  // 64 KB
    int tid = threadIdx.x;
    for (int i = tid; i < NF * NF / 4; i += 256)
        ((float4*)Ws)[i] = ((const float4*)W)[i];
    __syncthreads();

    float theta = logf((*lamda_p) / (float)(*l_p) + 1.0f);
    float omt = 1.0f - theta;

    int m0   = blockIdx.x * 32;
    int tcol = tid & 31;
    int trow = tid >> 5;
    int n    = tcol * 4;
    int mbase = m0 + trow * 4;

    int mr[4];
#pragma unroll
    for (int r = 0; r < 4; r++) {
        int m = mbase + r;
        mr[r] = (m < n_rows) ? m : (n_rows - 1);
    }

    float acc[4][4] = {};
    for (int k = 0; k < NF; k += 4) {
        float4 srow[4];
#pragma unroll
        for (int r = 0; r < 4; r++)
            srow[r] = *(const float4*)&sup[(size_t)mr[r] * NF + k];
#pragma unroll
        for (int kk = 0; kk < 4; kk++) {
            float4 w = *(const float4*)&Ws[(k + kk) * NF + n];
#pragma unroll
            for (int r = 0; r < 4; r++) {
                float s = (&srow[r].x)[kk];
                acc[r][0] += s * w.x;
                acc[r][1] += s * w.y;
                acc[r][2] += s * w.z;
                acc[r][3] += s * w.w;
            }
        }
    }

#pragma unroll
    for (int r = 0; r < 4; r++) {
        int m = mbase + r;
        if (m >= n_rows) break;
        float4 sv = *(const float4*)&sup[(size_t)m * NF + n];
        float4 iv = *(const float4*)&inp[(size_t)m * NF + n];
        float4 o;
        o.x = theta * acc[r][0] + omt * sv.x + iv.x;
        o.y = theta * acc[r][1] + omt * sv.y + iv.y;
        o.z = theta * acc[r][2] + omt * sv.z + iv.z;
        o.w = theta * acc[r][3] + omt * sv.w + iv.w;
        *(float4*)&out[(size_t)m * NF + n] = o;
    }
}

extern "C" void kernel_launch(void* const* d_in, const int* in_sizes, int n_in,
                              void* d_out, int out_size, void* d_ws, size_t ws_size,
                              hipStream_t stream) {
    const float* x       = (const float*)d_in[0];
    const float* h0      = (const float*)d_in[1];
    const int*   erow    = (const int*)d_in[2];
    const int*   ecol    = (const int*)d_in[3];
    const float* evalv   = (const float*)d_in[4];
    const float* W       = (const float*)d_in[5];
    const float* lamda_p = (const float*)d_in[6];
    const float* alpha_p = (const float*)d_in[7];
    const int*   l_p     = (const int*)d_in[8];

    int N_ = in_sizes[0] / NF;   // 50000
    int E_ = in_sizes[2];        // 800000
    int nb = (N_ + SCAN_B - 1) / SCAN_B;   // 49 (must be <= 64 for scanB)

    // workspace layout (256B-aligned slabs)
    char* ws = (char*)d_ws;
    size_t o = 0;
    auto alloc = [&](size_t bytes) { char* p = ws + o; o = (o + bytes + 255) & ~(size_t)255; return p; };
    float* sup  = (float*)alloc((size_t)N_ * NF * sizeof(float)); // 25.6 MB
    int*   cnt  = (int*)  alloc((size_t)N_ * sizeof(int));
    int*   off  = (int*)  alloc((size_t)(N_ + 1) * sizeof(int));
    int*   pos  = (int*)  alloc((size_t)N_ * sizeof(int));
    int*   scol = (int*)  alloc((size_t)E_ * sizeof(int));
    float* sval = (float*)alloc((size_t)E_ * sizeof(float));
    int*   bsum = (int*)  alloc((size_t)nb * sizeof(int));
    int*   bpre = (int*)  alloc((size_t)nb * sizeof(int));

    float* out = (float*)d_out;

    zero_kernel<<<(N_ + 255) / 256, 256, 0, stream>>>(cnt, N_);
    hist_kernel<<<(E_ + 255) / 256, 256, 0, stream>>>(erow, cnt, E_);
    scanA_kernel<<<nb, SCAN_B, 0, stream>>>(cnt, bsum, N_);
    scanB_kernel<<<1, 64, 0, stream>>>(bsum, bpre, off + N_, nb);
    scanC_kernel<<<nb, SCAN_B, 0, stream>>>(cnt, bpre, off, pos, N_);
    fill_kernel<<<(E_ + 255) / 256, 256, 0, stream>>>(erow, ecol, evalv, pos, scol, sval, E_);

    int blocks = (N_ * 64 + 255) / 256;   // one wave per row
    spmm_kernel<<<blocks, 256, 0, stream>>>(x, h0, off, scol, sval, sup, alpha_p, N_);

    gemm_epilogue_kernel<<<(N_ + 31) / 32, 256, 0, stream>>>(
        sup, W, x, out, lamda_p, l_p, N_);
}

// Round 7
// 294.577 us; speedup vs baseline: 5.0635x; 1.0560x over previous
//
#include <hip/hip_runtime.h>
#include <math.h>

#define NF 128      // feature dim (in == out == 128)
#define SCAN_B 1024 // scan chunk size

// ---- CSR build ------------------------------------------------------------

__global__ __launch_bounds__(256) void hist_kernel(
    const int* __restrict__ erow, int* __restrict__ cnt, int E_) {
    int e = blockIdx.x * 256 + threadIdx.x;
    if (e < E_) atomicAdd(&cnt[erow[e]], 1);
}

// Phase A: per-block sums of cnt chunks
__global__ __launch_bounds__(SCAN_B) void scanA_kernel(
    const int* __restrict__ cnt, int* __restrict__ bsum, int N_) {
    __shared__ int buf[SCAN_B];
    int t = threadIdx.x;
    int i = blockIdx.x * SCAN_B + t;
    buf[t] = (i < N_) ? cnt[i] : 0;
    __syncthreads();
    for (int d = SCAN_B / 2; d > 0; d >>= 1) {
        if (t < d) buf[t] += buf[t + d];
        __syncthreads();
    }
    if (t == 0) bsum[blockIdx.x] = buf[0];
}

// Phase C (scanB folded in): each block recomputes its own prefix from bsum
// (nb <= 64 so one wave-scan suffices), then chunk-scans cnt -> off[], pos[].
__global__ __launch_bounds__(SCAN_B) void scanC_kernel(
    const int* __restrict__ cnt, const int* __restrict__ bsum,
    int* __restrict__ off, int* __restrict__ pos, int N_, int nb) {
    __shared__ int buf[SCAN_B];
    __shared__ int bpre_sh;
    int t = threadIdx.x;
    if (t < 64) {
        int v0 = (t < nb) ? bsum[t] : 0;
        int v = v0;
        for (int d = 1; d < 64; d <<= 1) {
            int u = __shfl_up(v, d, 64);
            if (t >= d) v += u;
        }
        if (t == (int)blockIdx.x) bpre_sh = v - v0;          // exclusive prefix
        if (blockIdx.x == 0 && t == nb - 1) off[N_] = v;     // grand total
    }
    int i = blockIdx.x * SCAN_B + t;
    int v = (i < N_) ? cnt[i] : 0;
    buf[t] = v;
    __syncthreads();
    for (int d = 1; d < SCAN_B; d <<= 1) {
        int add = (t >= d) ? buf[t - d] : 0;
        __syncthreads();
        buf[t] += add;
        __syncthreads();
    }
    if (i < N_) {
        int o = bpre_sh + buf[t] - v;  // exclusive
        off[i] = o;
        pos[i] = o;
    }
}

// fill: single packed 8B scatter per edge (col,val) -> halves dirty-line traffic
__global__ __launch_bounds__(256) void fill_kernel(
    const int* __restrict__ erow, const int* __restrict__ ecol,
    const float* __restrict__ evalv, int* __restrict__ pos,
    int2* __restrict__ epack, int E_) {
    int e = blockIdx.x * 256 + threadIdx.x;
    if (e >= E_) return;
    int p = atomicAdd(&pos[erow[e]], 1);
    int2 pk;
    pk.x = ecol[e];
    pk.y = __float_as_int(evalv[e]);
    epack[p] = pk;
}

// ---- SpMM: one wave per row; float4 gathers, 2 edges per wave-instruction --
// lanes 0..31 gather even-local edges, lanes 32..63 odd-local edges; halves
// combined with shfl_xor(32). Single 512B write per row from lanes 0..31.

__global__ __launch_bounds__(256) void spmm_kernel(
    const float* __restrict__ x, const float* __restrict__ h0,
    const int* __restrict__ off, const int2* __restrict__ epack,
    float* __restrict__ sup, const float* __restrict__ alpha_p, int N_) {
    int w = (blockIdx.x * 256 + threadIdx.x) >> 6;   // wave id == row
    if (w >= N_) return;
    int lane = threadIdx.x & 63;
    int sub  = lane & 31;     // feature quad index
    int half = lane >> 5;     // which edge-parity this lane handles
    int s = off[w], e = off[w + 1];
    float4 acc = {0.f, 0.f, 0.f, 0.f};
    int i = s + half;
    // 2-deep unroll per half -> 4 edges in flight per wave iteration
    for (; i + 2 < e; i += 4) {
        int2 e0 = epack[i];
        int2 e1 = epack[i + 2];
        float v0 = __int_as_float(e0.y);
        float v1 = __int_as_float(e1.y);
        float4 a = *((const float4*)(x + (size_t)e0.x * NF) + sub);
        float4 b = *((const float4*)(x + (size_t)e1.x * NF) + sub);
        acc.x += v0 * a.x + v1 * b.x;
        acc.y += v0 * a.y + v1 * b.y;
        acc.z += v0 * a.z + v1 * b.z;
        acc.w += v0 * a.w + v1 * b.w;
    }
    for (; i < e; i += 2) {
        int2 e0 = epack[i];
        float v0 = __int_as_float(e0.y);
        float4 a = *((const float4*)(x + (size_t)e0.x * NF) + sub);
        acc.x += v0 * a.x;
        acc.y += v0 * a.y;
        acc.z += v0 * a.z;
        acc.w += v0 * a.w;
    }
    // combine the two halves (lane ^ 32 holds the other parity's partial)
    acc.x += __shfl_xor(acc.x, 32, 64);
    acc.y += __shfl_xor(acc.y, 32, 64);
    acc.z += __shfl_xor(acc.z, 32, 64);
    acc.w += __shfl_xor(acc.w, 32, 64);
    if (half == 0) {
        float alpha = *alpha_p;
        float oma = 1.0f - alpha;
        float4 h = *((const float4*)(h0 + (size_t)w * NF) + sub);
        float4 o;
        o.x = oma * acc.x + alpha * h.x;
        o.y = oma * acc.y + alpha * h.y;
        o.z = oma * acc.z + alpha * h.z;
        o.w = oma * acc.w + alpha * h.w;
        *((float4*)(sup + (size_t)w * NF) + sub) = o;
    }
}

// ---- GEMM + epilogue: out = theta*(sup@W) + (1-theta)*sup + input ---------

__global__ __launch_bounds__(256) void gemm_epilogue_kernel(
    const float* __restrict__ sup, const float* __restrict__ W,
    const float* __restrict__ inp, float* __restrict__ out,
    const float* __restrict__ lamda_p, const int* __restrict__ l_p, int n_rows) {
    __shared__ float Ws[NF * NF];  // 64 KB
    int tid = threadIdx.x;
    for (int i = tid; i < NF * NF / 4; i += 256)
        ((float4*)Ws)[i] = ((const float4*)W)[i];
    __syncthreads();

    float theta = logf((*lamda_p) / (float)(*l_p) + 1.0f);
    float omt = 1.0f - theta;

    int m0   = blockIdx.x * 32;
    int tcol = tid & 31;
    int trow = tid >> 5;
    int n    = tcol * 4;
    int mbase = m0 + trow * 4;

    int mr[4];
#pragma unroll
    for (int r = 0; r < 4; r++) {
        int m = mbase + r;
        mr[r] = (m < n_rows) ? m : (n_rows - 1);
    }

    float acc[4][4] = {};
    for (int k = 0; k < NF; k += 4) {
        float4 srow[4];
#pragma unroll
        for (int r = 0; r < 4; r++)
            srow[r] = *(const float4*)&sup[(size_t)mr[r] * NF + k];
#pragma unroll
        for (int kk = 0; kk < 4; kk++) {
            float4 w = *(const float4*)&Ws[(k + kk) * NF + n];
#pragma unroll
            for (int r = 0; r < 4; r++) {
                float s = (&srow[r].x)[kk];
                acc[r][0] += s * w.x;
                acc[r][1] += s * w.y;
                acc[r][2] += s * w.z;
                acc[r][3] += s * w.w;
            }
        }
    }

#pragma unroll
    for (int r = 0; r < 4; r++) {
        int m = mbase + r;
        if (m >= n_rows) break;
        float4 sv = *(const float4*)&sup[(size_t)m * NF + n];
        float4 iv = *(const float4*)&inp[(size_t)m * NF + n];
        float4 o;
        o.x = theta * acc[r][0] + omt * sv.x + iv.x;
        o.y = theta * acc[r][1] + omt * sv.y + iv.y;
        o.z = theta * acc[r][2] + omt * sv.z + iv.z;
        o.w = theta * acc[r][3] + omt * sv.w + iv.w;
        *(float4*)&out[(size_t)m * NF + n] = o;
    }
}

extern "C" void kernel_launch(void* const* d_in, const int* in_sizes, int n_in,
                              void* d_out, int out_size, void* d_ws, size_t ws_size,
                              hipStream_t stream) {
    const float* x       = (const float*)d_in[0];
    const float* h0      = (const float*)d_in[1];
    const int*   erow    = (const int*)d_in[2];
    const int*   ecol    = (const int*)d_in[3];
    const float* evalv   = (const float*)d_in[4];
    const float* W       = (const float*)d_in[5];
    const float* lamda_p = (const float*)d_in[6];
    const float* alpha_p = (const float*)d_in[7];
    const int*   l_p     = (const int*)d_in[8];

    int N_ = in_sizes[0] / NF;   // 50000
    int E_ = in_sizes[2];        // 800000
    int nb = (N_ + SCAN_B - 1) / SCAN_B;   // 49 (must be <= 64)

    // workspace layout (256B-aligned slabs)
    char* ws = (char*)d_ws;
    size_t o = 0;
    auto alloc = [&](size_t bytes) { char* p = ws + o; o = (o + bytes + 255) & ~(size_t)255; return p; };
    float* sup   = (float*)alloc((size_t)N_ * NF * sizeof(float)); // 25.6 MB
    int*   cnt   = (int*)  alloc((size_t)N_ * sizeof(int));
    int*   off   = (int*)  alloc((size_t)(N_ + 1) * sizeof(int));
    int*   pos   = (int*)  alloc((size_t)N_ * sizeof(int));
    int2*  epack = (int2*) alloc((size_t)E_ * sizeof(int2));
    int*   bsum  = (int*)  alloc((size_t)nb * sizeof(int));

    float* out = (float*)d_out;

    hipMemsetAsync(cnt, 0, (size_t)N_ * sizeof(int), stream);
    hist_kernel<<<(E_ + 255) / 256, 256, 0, stream>>>(erow, cnt, E_);
    scanA_kernel<<<nb, SCAN_B, 0, stream>>>(cnt, bsum, N_);
    scanC_kernel<<<nb, SCAN_B, 0, stream>>>(cnt, bsum, off, pos, N_, nb);
    fill_kernel<<<(E_ + 255) / 256, 256, 0, stream>>>(erow, ecol, evalv, pos, epack, E_);

    int blocks = (N_ * 64 + 255) / 256;   // one wave per row
    spmm_kernel<<<blocks, 256, 0, stream>>>(x, h0, off, epack, sup, alpha_p, N_);

    gemm_epilogue_kernel<<<(N_ + 31) / 32, 256, 0, stream>>>(
        sup, W, x, out, lamda_p, l_p, N_);
}

// Round 12
// 275.880 us; speedup vs baseline: 5.4067x; 1.0678x over previous
//
#include <hip/hip_runtime.h>
#include <math.h>

#define NF 128      // feature dim (in == out == 128)
#define SCAN_B 1024 // scan chunk size

// ---- bf16 helpers ---------------------------------------------------------

__device__ __forceinline__ unsigned short f2bf(float f) {
    unsigned int u = __float_as_uint(f);
    u = (u + 0x7fffu + ((u >> 16) & 1u)) >> 16;   // round-to-nearest-even
    return (unsigned short)u;
}

// x (fp32) -> xb (bf16 packed, 2 per uint). 8 floats per thread.
__global__ __launch_bounds__(256) void cvt_kernel(
    const float* __restrict__ x, uint* __restrict__ xb, int n8) {
    int i = blockIdx.x * 256 + threadIdx.x;
    if (i >= n8) return;
    float4 a = ((const float4*)x)[i * 2];
    float4 b = ((const float4*)x)[i * 2 + 1];
    uint4 o;
    o.x = (uint)f2bf(a.x) | ((uint)f2bf(a.y) << 16);
    o.y = (uint)f2bf(a.z) | ((uint)f2bf(a.w) << 16);
    o.z = (uint)f2bf(b.x) | ((uint)f2bf(b.y) << 16);
    o.w = (uint)f2bf(b.z) | ((uint)f2bf(b.w) << 16);
    ((uint4*)xb)[i] = o;
}

// ---- CSR build ------------------------------------------------------------

__global__ __launch_bounds__(256) void hist_kernel(
    const int* __restrict__ erow, int* __restrict__ cnt, int E_) {
    int e = blockIdx.x * 256 + threadIdx.x;
    if (e < E_) atomicAdd(&cnt[erow[e]], 1);
}

// Phase A: per-block sums of cnt chunks
__global__ __launch_bounds__(SCAN_B) void scanA_kernel(
    const int* __restrict__ cnt, int* __restrict__ bsum, int N_) {
    __shared__ int buf[SCAN_B];
    int t = threadIdx.x;
    int i = blockIdx.x * SCAN_B + t;
    buf[t] = (i < N_) ? cnt[i] : 0;
    __syncthreads();
    for (int d = SCAN_B / 2; d > 0; d >>= 1) {
        if (t < d) buf[t] += buf[t + d];
        __syncthreads();
    }
    if (t == 0) bsum[blockIdx.x] = buf[0];
}

// Phase C: each block wave-scans bsum (nb<=64) for its prefix, then
// chunk-scans cnt -> off[], pos[].
__global__ __launch_bounds__(SCAN_B) void scanC_kernel(
    const int* __restrict__ cnt, const int* __restrict__ bsum,
    int* __restrict__ off, int* __restrict__ pos, int N_, int nb) {
    __shared__ int buf[SCAN_B];
    __shared__ int bpre_sh;
    int t = threadIdx.x;
    if (t < 64) {
        int v0 = (t < nb) ? bsum[t] : 0;
        int v = v0;
        for (int d = 1; d < 64; d <<= 1) {
            int u = __shfl_up(v, d, 64);
            if (t >= d) v += u;
        }
        if (t == (int)blockIdx.x) bpre_sh = v - v0;          // exclusive prefix
        if (blockIdx.x == 0 && t == nb - 1) off[N_] = v;     // grand total
    }
    int i = blockIdx.x * SCAN_B + t;
    int v = (i < N_) ? cnt[i] : 0;
    buf[t] = v;
    __syncthreads();
    for (int d = 1; d < SCAN_B; d <<= 1) {
        int add = (t >= d) ? buf[t - d] : 0;
        __syncthreads();
        buf[t] += add;
        __syncthreads();
    }
    if (i < N_) {
        int o = bpre_sh + buf[t] - v;  // exclusive
        off[i] = o;
        pos[i] = o;
    }
}

// fill: single packed 8B scatter per edge (col,val)
__global__ __launch_bounds__(256) void fill_kernel(
    const int* __restrict__ erow, const int* __restrict__ ecol,
    const float* __restrict__ evalv, int* __restrict__ pos,
    int2* __restrict__ epack, int E_) {
    int e = blockIdx.x * 256 + threadIdx.x;
    if (e >= E_) return;
    int p = atomicAdd(&pos[erow[e]], 1);
    int2 pk;
    pk.x = ecol[e];
    pk.y = __float_as_int(evalv[e]);
    epack[p] = pk;
}

// ---- SpMM: one wave per row; bf16 gathers, 16 lanes per edge --------------
// 4 edge-groups per wave (g = lane>>4), each lane loads ushort8 = 8 feats.
// 2-deep unroll -> 8 gathers in flight. Groups combined via shfl_xor(16,32).

#define UNPK_FMA(u, v, a0, a1)                         \
    a0 += (v) * __uint_as_float((u) << 16);            \
    a1 += (v) * __uint_as_float((u) & 0xffff0000u);

__global__ __launch_bounds__(256) void spmm_kernel(
    const unsigned short* __restrict__ xb, const float* __restrict__ h0,
    const int* __restrict__ off, const int2* __restrict__ epack,
    float* __restrict__ sup, const float* __restrict__ alpha_p, int N_) {
    int w = (blockIdx.x * 256 + threadIdx.x) >> 6;   // wave id == row
    if (w >= N_) return;
    int lane = threadIdx.x & 63;
    int g    = lane >> 4;      // edge-group 0..3
    int seg  = lane & 15;      // 8-feature segment
    int s = off[w], e = off[w + 1];
    float acc[8] = {};
    int i = s + g;
    for (; i + 4 < e; i += 8) {    // edges i and i+4 for this group
        int2 e0 = epack[i];
        int2 e1 = epack[i + 4];
        float v0 = __int_as_float(e0.y);
        float v1 = __int_as_float(e1.y);
        uint4 a = *(const uint4*)(xb + (size_t)e0.x * NF + seg * 8);
        uint4 b = *(const uint4*)(xb + (size_t)e1.x * NF + seg * 8);
        UNPK_FMA(a.x, v0, acc[0], acc[1]);
        UNPK_FMA(a.y, v0, acc[2], acc[3]);
        UNPK_FMA(a.z, v0, acc[4], acc[5]);
        UNPK_FMA(a.w, v0, acc[6], acc[7]);
        UNPK_FMA(b.x, v1, acc[0], acc[1]);
        UNPK_FMA(b.y, v1, acc[2], acc[3]);
        UNPK_FMA(b.z, v1, acc[4], acc[5]);
        UNPK_FMA(b.w, v1, acc[6], acc[7]);
    }
    if (i < e) {
        int2 e0 = epack[i];
        float v0 = __int_as_float(e0.y);
        uint4 a = *(const uint4*)(xb + (size_t)e0.x * NF + seg * 8);
        UNPK_FMA(a.x, v0, acc[0], acc[1]);
        UNPK_FMA(a.y, v0, acc[2], acc[3]);
        UNPK_FMA(a.z, v0, acc[4], acc[5]);
        UNPK_FMA(a.w, v0, acc[6], acc[7]);
    }
#pragma unroll
    for (int j = 0; j < 8; j++) {
        acc[j] += __shfl_xor(acc[j], 16, 64);
        acc[j] += __shfl_xor(acc[j], 32, 64);
    }
    if (g == 0) {
        float alpha = *alpha_p;
        float oma = 1.0f - alpha;
        const float* h = h0 + (size_t)w * NF + seg * 8;
        float4 ha = *(const float4*)h;
        float4 hb = *(const float4*)(h + 4);
        float4 o1, o2;
        o1.x = oma * acc[0] + alpha * ha.x;
        o1.y = oma * acc[1] + alpha * ha.y;
        o1.z = oma * acc[2] + alpha * ha.z;
        o1.w = oma * acc[3] + alpha * ha.w;
        o2.x = oma * acc[4] + alpha * hb.x;
        o2.y = oma * acc[5] + alpha * hb.y;
        o2.z = oma * acc[6] + alpha * hb.z;
        o2.w = oma * acc[7] + alpha * hb.w;
        float* d = sup + (size_t)w * NF + seg * 8;
        *(float4*)d = o1;
        *(float4*)(d + 4) = o2;
    }
}

// ---- GEMM + epilogue: out = theta*(sup@W) + (1-theta)*sup + input ---------

__global__ __launch_bounds__(256) void gemm_epilogue_kernel(
    const float* __restrict__ sup, const float* __restrict__ W,
    const float* __restrict__ inp, float* __restrict__ out,
    const float* __restrict__ lamda_p, const int* __restrict__ l_p, int n_rows) {
    __shared__ float Ws[NF * NF];  // 64 KB
    int tid = threadIdx.x;
    for (int i = tid; i < NF * NF / 4; i += 256)
        ((float4*)Ws)[i] = ((const float4*)W)[i];
    __syncthreads();

    float theta = logf((*lamda_p) / (float)(*l_p) + 1.0f);
    float omt = 1.0f - theta;

    int m0   = blockIdx.x * 32;
    int tcol = tid & 31;
    int trow = tid >> 5;
    int n    = tcol * 4;
    int mbase = m0 + trow * 4;

    int mr[4];
#pragma unroll
    for (int r = 0; r < 4; r++) {
        int m = mbase + r;
        mr[r] = (m < n_rows) ? m : (n_rows - 1);
    }

    float acc[4][4] = {};
    for (int k = 0; k < NF; k += 4) {
        float4 srow[4];
#pragma unroll
        for (int r = 0; r < 4; r++)
            srow[r] = *(const float4*)&sup[(size_t)mr[r] * NF + k];
#pragma unroll
        for (int kk = 0; kk < 4; kk++) {
            float4 w = *(const float4*)&Ws[(k + kk) * NF + n];
#pragma unroll
            for (int r = 0; r < 4; r++) {
                float s = (&srow[r].x)[kk];
                acc[r][0] += s * w.x;
                acc[r][1] += s * w.y;
                acc[r][2] += s * w.z;
                acc[r][3] += s * w.w;
            }
        }
    }

#pragma unroll
    for (int r = 0; r < 4; r++) {
        int m = mbase + r;
        if (m >= n_rows) break;
        float4 sv = *(const float4*)&sup[(size_t)m * NF + n];
        float4 iv = *(const float4*)&inp[(size_t)m * NF + n];
        float4 o;
        o.x = theta * acc[r][0] + omt * sv.x + iv.x;
        o.y = theta * acc[r][1] + omt * sv.y + iv.y;
        o.z = theta * acc[r][2] + omt * sv.z + iv.z;
        o.w = theta * acc[r][3] + omt * sv.w + iv.w;
        *(float4*)&out[(size_t)m * NF + n] = o;
    }
}

extern "C" void kernel_launch(void* const* d_in, const int* in_sizes, int n_in,
                              void* d_out, int out_size, void* d_ws, size_t ws_size,
                              hipStream_t stream) {
    const float* x       = (const float*)d_in[0];
    const float* h0      = (const float*)d_in[1];
    const int*   erow    = (const int*)d_in[2];
    const int*   ecol    = (const int*)d_in[3];
    const float* evalv   = (const float*)d_in[4];
    const float* W       = (const float*)d_in[5];
    const float* lamda_p = (const float*)d_in[6];
    const float* alpha_p = (const float*)d_in[7];
    const int*   l_p     = (const int*)d_in[8];

    int N_ = in_sizes[0] / NF;   // 50000
    int E_ = in_sizes[2];        // 800000
    int nb = (N_ + SCAN_B - 1) / SCAN_B;   // 49 (must be <= 64)

    // workspace layout (256B-aligned slabs)
    char* ws = (char*)d_ws;
    size_t o = 0;
    auto alloc = [&](size_t bytes) { char* p = ws + o; o = (o + bytes + 255) & ~(size_t)255; return p; };
    float* sup   = (float*)alloc((size_t)N_ * NF * sizeof(float));      // 25.6 MB
    unsigned short* xb = (unsigned short*)alloc((size_t)N_ * NF * 2);   // 12.8 MB
    int*   cnt   = (int*)  alloc((size_t)N_ * sizeof(int));
    int*   off   = (int*)  alloc((size_t)(N_ + 1) * sizeof(int));
    int*   pos   = (int*)  alloc((size_t)N_ * sizeof(int));
    int2*  epack = (int2*) alloc((size_t)E_ * sizeof(int2));
    int*   bsum  = (int*)  alloc((size_t)nb * sizeof(int));

    float* out = (float*)d_out;

    int n8 = N_ * NF / 8;
    cvt_kernel<<<(n8 + 255) / 256, 256, 0, stream>>>(x, (uint*)xb, n8);

    hipMemsetAsync(cnt, 0, (size_t)N_ * sizeof(int), stream);
    hist_kernel<<<(E_ + 255) / 256, 256, 0, stream>>>(erow, cnt, E_);
    scanA_kernel<<<nb, SCAN_B, 0, stream>>>(cnt, bsum, N_);
    scanC_kernel<<<nb, SCAN_B, 0, stream>>>(cnt, bsum, off, pos, N_, nb);
    fill_kernel<<<(E_ + 255) / 256, 256, 0, stream>>>(erow, ecol, evalv, pos, epack, E_);

    int blocks = (N_ * 64 + 255) / 256;   // one wave per row
    spmm_kernel<<<blocks, 256, 0, stream>>>(xb, h0, off, epack, sup, alpha_p, N_);

    gemm_epilogue_kernel<<<(N_ + 31) / 32, 256, 0, stream>>>(
        sup, W, x, out, lamda_p, l_p, N_);
}

// Round 15
// 261.005 us; speedup vs baseline: 5.7148x; 1.0570x over previous
//
#include <hip/hip_runtime.h>
#include <math.h>

#define NF 128      // feature dim (in == out == 128)
#define SCAN_B 1024 // scan chunk size

typedef __bf16 bf16x8 __attribute__((ext_vector_type(8)));
typedef float  f32x4  __attribute__((ext_vector_type(4)));

// ---- bf16 helpers ---------------------------------------------------------

__device__ __forceinline__ unsigned short f2bf(float f) {
    unsigned int u = __float_as_uint(f);
    u = (u + 0x7fffu + ((u >> 16) & 1u)) >> 16;   // round-to-nearest-even
    return (unsigned short)u;
}
__device__ __forceinline__ float bf2f(unsigned short s) {
    return __uint_as_float((unsigned int)s << 16);
}

// x (fp32) -> xb (bf16 packed, 2 per uint). 8 floats per thread.
__global__ __launch_bounds__(256) void cvt_kernel(
    const float* __restrict__ x, uint* __restrict__ xb, int n8) {
    int i = blockIdx.x * 256 + threadIdx.x;
    if (i >= n8) return;
    float4 a = ((const float4*)x)[i * 2];
    float4 b = ((const float4*)x)[i * 2 + 1];
    uint4 o;
    o.x = (uint)f2bf(a.x) | ((uint)f2bf(a.y) << 16);
    o.y = (uint)f2bf(a.z) | ((uint)f2bf(a.w) << 16);
    o.z = (uint)f2bf(b.x) | ((uint)f2bf(b.y) << 16);
    o.w = (uint)f2bf(b.z) | ((uint)f2bf(b.w) << 16);
    ((uint4*)xb)[i] = o;
}

// W fp32 [k][n] -> Wt bf16 [n][k]  (transposed so MFMA B-frags are unit-stride)
__global__ __launch_bounds__(256) void cvtW_kernel(
    const float* __restrict__ W, unsigned short* __restrict__ Wt) {
    int idx = blockIdx.x * 256 + threadIdx.x;   // 16384 total
    int k = idx >> 7, n = idx & 127;
    Wt[n * NF + k] = f2bf(W[k * NF + n]);
}

// ---- CSR build ------------------------------------------------------------

__global__ __launch_bounds__(256) void hist_kernel(
    const int* __restrict__ erow, int* __restrict__ cnt, int E_) {
    int e = blockIdx.x * 256 + threadIdx.x;
    if (e < E_) atomicAdd(&cnt[erow[e]], 1);
}

// Phase A: per-block sums of cnt chunks
__global__ __launch_bounds__(SCAN_B) void scanA_kernel(
    const int* __restrict__ cnt, int* __restrict__ bsum, int N_) {
    __shared__ int buf[SCAN_B];
    int t = threadIdx.x;
    int i = blockIdx.x * SCAN_B + t;
    buf[t] = (i < N_) ? cnt[i] : 0;
    __syncthreads();
    for (int d = SCAN_B / 2; d > 0; d >>= 1) {
        if (t < d) buf[t] += buf[t + d];
        __syncthreads();
    }
    if (t == 0) bsum[blockIdx.x] = buf[0];
}

// Phase C: each block wave-scans bsum (nb<=64) for its prefix, then
// chunk-scans cnt -> off[], pos[].
__global__ __launch_bounds__(SCAN_B) void scanC_kernel(
    const int* __restrict__ cnt, const int* __restrict__ bsum,
    int* __restrict__ off, int* __restrict__ pos, int N_, int nb) {
    __shared__ int buf[SCAN_B];
    __shared__ int bpre_sh;
    int t = threadIdx.x;
    if (t < 64) {
        int v0 = (t < nb) ? bsum[t] : 0;
        int v = v0;
        for (int d = 1; d < 64; d <<= 1) {
            int u = __shfl_up(v, d, 64);
            if (t >= d) v += u;
        }
        if (t == (int)blockIdx.x) bpre_sh = v - v0;          // exclusive prefix
        if (blockIdx.x == 0 && t == nb - 1) off[N_] = v;     // grand total
    }
    int i = blockIdx.x * SCAN_B + t;
    int v = (i < N_) ? cnt[i] : 0;
    buf[t] = v;
    __syncthreads();
    for (int d = 1; d < SCAN_B; d <<= 1) {
        int add = (t >= d) ? buf[t - d] : 0;
        __syncthreads();
        buf[t] += add;
        __syncthreads();
    }
    if (i < N_) {
        int o = bpre_sh + buf[t] - v;  // exclusive
        off[i] = o;
        pos[i] = o;
    }
}

// fill: single packed 8B scatter per edge (col,val)
__global__ __launch_bounds__(256) void fill_kernel(
    const int* __restrict__ erow, const int* __restrict__ ecol,
    const float* __restrict__ evalv, int* __restrict__ pos,
    int2* __restrict__ epack, int E_) {
    int e = blockIdx.x * 256 + threadIdx.x;
    if (e >= E_) return;
    int p = atomicAdd(&pos[erow[e]], 1);
    int2 pk;
    pk.x = ecol[e];
    pk.y = __float_as_int(evalv[e]);
    epack[p] = pk;
}

// ---- SpMM: one wave per row; bf16 gathers, 16 lanes per edge --------------
// Output written as bf16 (supb) -> feeds MFMA GEMM directly.

#define UNPK_FMA(u, v, a0, a1)                         \
    a0 += (v) * __uint_as_float((u) << 16);            \
    a1 += (v) * __uint_as_float((u) & 0xffff0000u);

__global__ __launch_bounds__(256) void spmm_kernel(
    const unsigned short* __restrict__ xb, const float* __restrict__ h0,
    const int* __restrict__ off, const int2* __restrict__ epack,
    unsigned short* __restrict__ supb, const float* __restrict__ alpha_p, int N_) {
    int w = (blockIdx.x * 256 + threadIdx.x) >> 6;   // wave id == row
    if (w >= N_) return;
    int lane = threadIdx.x & 63;
    int g    = lane >> 4;      // edge-group 0..3
    int seg  = lane & 15;      // 8-feature segment
    int s = off[w], e = off[w + 1];
    float acc[8] = {};
    int i = s + g;
    for (; i + 4 < e; i += 8) {    // edges i and i+4 for this group
        int2 e0 = epack[i];
        int2 e1 = epack[i + 4];
        float v0 = __int_as_float(e0.y);
        float v1 = __int_as_float(e1.y);
        uint4 a = *(const uint4*)(xb + (size_t)e0.x * NF + seg * 8);
        uint4 b = *(const uint4*)(xb + (size_t)e1.x * NF + seg * 8);
        UNPK_FMA(a.x, v0, acc[0], acc[1]);
        UNPK_FMA(a.y, v0, acc[2], acc[3]);
        UNPK_FMA(a.z, v0, acc[4], acc[5]);
        UNPK_FMA(a.w, v0, acc[6], acc[7]);
        UNPK_FMA(b.x, v1, acc[0], acc[1]);
        UNPK_FMA(b.y, v1, acc[2], acc[3]);
        UNPK_FMA(b.z, v1, acc[4], acc[5]);
        UNPK_FMA(b.w, v1, acc[6], acc[7]);
    }
    if (i < e) {
        int2 e0 = epack[i];
        float v0 = __int_as_float(e0.y);
        uint4 a = *(const uint4*)(xb + (size_t)e0.x * NF + seg * 8);
        UNPK_FMA(a.x, v0, acc[0], acc[1]);
        UNPK_FMA(a.y, v0, acc[2], acc[3]);
        UNPK_FMA(a.z, v0, acc[4], acc[5]);
        UNPK_FMA(a.w, v0, acc[6], acc[7]);
    }
#pragma unroll
    for (int j = 0; j < 8; j++) {
        acc[j] += __shfl_xor(acc[j], 16, 64);
        acc[j] += __shfl_xor(acc[j], 32, 64);
    }
    if (g == 0) {
        float alpha = *alpha_p;
        float oma = 1.0f - alpha;
        const float* h = h0 + (size_t)w * NF + seg * 8;
        float4 ha = *(const float4*)h;
        float4 hb = *(const float4*)(h + 4);
        float o0 = oma * acc[0] + alpha * ha.x;
        float o1 = oma * acc[1] + alpha * ha.y;
        float o2 = oma * acc[2] + alpha * ha.z;
        float o3 = oma * acc[3] + alpha * ha.w;
        float o4 = oma * acc[4] + alpha * hb.x;
        float o5 = oma * acc[5] + alpha * hb.y;
        float o6 = oma * acc[6] + alpha * hb.z;
        float o7 = oma * acc[7] + alpha * hb.w;
        uint4 pk;
        pk.x = (uint)f2bf(o0) | ((uint)f2bf(o1) << 16);
        pk.y = (uint)f2bf(o2) | ((uint)f2bf(o3) << 16);
        pk.z = (uint)f2bf(o4) | ((uint)f2bf(o5) << 16);
        pk.w = (uint)f2bf(o6) | ((uint)f2bf(o7) << 16);
        *(uint4*)(supb + (size_t)w * NF + seg * 8) = pk;
    }
}

// ---- MFMA GEMM + epilogue: out = theta*(supb@W) + (1-theta)*supb + x ------
// Block = 256 threads = 4 waves; wave handles a 16-row stripe x 128 cols.
// A-frag: supb rows (unit-stride bf16x8). B-frag: Wt = W^T (unit-stride).
// Both use identical lane->k mapping so any k-permutation cancels.
// D layout (HW-verified): col = lane&15, row = (lane>>4)*4 + reg.

__global__ __launch_bounds__(256) void gemm_mfma_kernel(
    const unsigned short* __restrict__ supb, const unsigned short* __restrict__ Wt,
    const float* __restrict__ x, float* __restrict__ out,
    const float* __restrict__ lamda_p, const int* __restrict__ l_p, int n_rows) {
    int wave = threadIdx.x >> 6;
    int lane = threadIdx.x & 63;
    int m0 = blockIdx.x * 64 + wave * 16;
    if (m0 >= n_rows) return;     // n_rows % 16 == 0: tiles never straddle

    float theta = logf((*lamda_p) / (float)(*l_p) + 1.0f);
    float omt = 1.0f - theta;

    int lr = lane & 15;   // A row-offset / B col / D col
    int kg = lane >> 4;   // k-group

    // A-frags: 4 k-tiles of 32 (each lane: 8 contiguous bf16)
    bf16x8 afr[4];
    const unsigned short* abase = supb + (size_t)(m0 + lr) * NF + kg * 8;
#pragma unroll
    for (int kt = 0; kt < 4; kt++)
        afr[kt] = *reinterpret_cast<const bf16x8*>(abase + kt * 32);

#pragma unroll
    for (int nt = 0; nt < 8; nt++) {
        int n0 = nt * 16;
        const unsigned short* bbase = Wt + (size_t)(n0 + lr) * NF + kg * 8;
        f32x4 acc = {0.f, 0.f, 0.f, 0.f};
#pragma unroll
        for (int kt = 0; kt < 4; kt++) {
            bf16x8 bfr = *reinterpret_cast<const bf16x8*>(bbase + kt * 32);
            acc = __builtin_amdgcn_mfma_f32_16x16x32_bf16(afr[kt], bfr, acc, 0, 0, 0);
        }
        int ncol = n0 + lr;
#pragma unroll
        for (int j = 0; j < 4; j++) {
            int m = m0 + kg * 4 + j;
            float sv = bf2f(supb[(size_t)m * NF + ncol]);
            float xv = x[(size_t)m * NF + ncol];
            out[(size_t)m * NF + ncol] = theta * acc[j] + omt * sv + xv;
        }
    }
}

extern "C" void kernel_launch(void* const* d_in, const int* in_sizes, int n_in,
                              void* d_out, int out_size, void* d_ws, size_t ws_size,
                              hipStream_t stream) {
    const float* x       = (const float*)d_in[0];
    const float* h0      = (const float*)d_in[1];
    const int*   erow    = (const int*)d_in[2];
    const int*   ecol    = (const int*)d_in[3];
    const float* evalv   = (const float*)d_in[4];
    const float* W       = (const float*)d_in[5];
    const float* lamda_p = (const float*)d_in[6];
    const float* alpha_p = (const float*)d_in[7];
    const int*   l_p     = (const int*)d_in[8];

    int N_ = in_sizes[0] / NF;   // 50000
    int E_ = in_sizes[2];        // 800000
    int nb = (N_ + SCAN_B - 1) / SCAN_B;   // 49 (must be <= 64)

    // workspace layout (256B-aligned slabs)
    char* ws = (char*)d_ws;
    size_t o = 0;
    auto alloc = [&](size_t bytes) { char* p = ws + o; o = (o + bytes + 255) & ~(size_t)255; return p; };
    unsigned short* supb = (unsigned short*)alloc((size_t)N_ * NF * 2);  // 12.8 MB
    unsigned short* xb   = (unsigned short*)alloc((size_t)N_ * NF * 2);  // 12.8 MB
    unsigned short* Wt   = (unsigned short*)alloc((size_t)NF * NF * 2);  // 32 KB
    int*   cnt   = (int*)  alloc((size_t)N_ * sizeof(int));
    int*   off   = (int*)  alloc((size_t)(N_ + 1) * sizeof(int));
    int*   pos   = (int*)  alloc((size_t)N_ * sizeof(int));
    int2*  epack = (int2*) alloc((size_t)E_ * sizeof(int2));
    int*   bsum  = (int*)  alloc((size_t)nb * sizeof(int));

    float* out = (float*)d_out;

    int n8 = N_ * NF / 8;
    cvt_kernel<<<(n8 + 255) / 256, 256, 0, stream>>>(x, (uint*)xb, n8);
    cvtW_kernel<<<NF * NF / 256, 256, 0, stream>>>(W, Wt);

    hipMemsetAsync(cnt, 0, (size_t)N_ * sizeof(int), stream);
    hist_kernel<<<(E_ + 255) / 256, 256, 0, stream>>>(erow, cnt, E_);
    scanA_kernel<<<nb, SCAN_B, 0, stream>>>(cnt, bsum, N_);
    scanC_kernel<<<nb, SCAN_B, 0, stream>>>(cnt, bsum, off, pos, N_, nb);
    fill_kernel<<<(E_ + 255) / 256, 256, 0, stream>>>(erow, ecol, evalv, pos, epack, E_);

    int blocks = (N_ * 64 + 255) / 256;   // one wave per row
    spmm_kernel<<<blocks, 256, 0, stream>>>(xb, h0, off, epack, supb, alpha_p, N_);

    gemm_mfma_kernel<<<(N_ + 63) / 64, 256, 0, stream>>>(
        supb, Wt, x, out, lamda_p, l_p, N_);
}